// Round 1
// baseline (270.804 us; speedup 1.0000x reference)
//
#include <hip/hip_runtime.h>
#include <math.h>

#define NN 100000
#define MM 50000
#define EE 600000
#define DD 128
#define NB 196     // ceil(MM/256)
#define NNP 100096 // NN padded to block multiple
#define EE4 750000 // padded edge capacity: EE + 3*MM

typedef short bf16x8 __attribute__((ext_vector_type(8)));
typedef float f32x4 __attribute__((ext_vector_type(4)));

// ---- bf16 helpers (upper 16 bits of f32; RNE rounding) ----
__device__ __forceinline__ float bl(unsigned u) { return __uint_as_float(u << 16); }
__device__ __forceinline__ float bh(unsigned u) { return __uint_as_float(u & 0xFFFF0000u); }
__device__ __forceinline__ unsigned rne(float f) {
    unsigned u = __float_as_uint(f);
    return (u + 0x7FFFu + ((u >> 16) & 1u)) >> 16;
}
__device__ __forceinline__ unsigned pk2(float a, float b) { return rne(a) | (rne(b) << 16); }

// a[0..7] += v * bf16x8(u)   (spmm inner op)
__device__ __forceinline__ void fmab8(float v, uint4 u, float* a) {
    a[0] = fmaf(v, bl(u.x), a[0]); a[1] = fmaf(v, bh(u.x), a[1]);
    a[2] = fmaf(v, bl(u.y), a[2]); a[3] = fmaf(v, bh(u.y), a[3]);
    a[4] = fmaf(v, bl(u.z), a[4]); a[5] = fmaf(v, bh(u.z), a[5]);
    a[6] = fmaf(v, bl(u.w), a[6]); a[7] = fmaf(v, bh(u.w), a[7]);
}

__device__ __forceinline__ void fma21(float h, const float* wrow, float* a) {
    #pragma unroll
    for (int j = 0; j < 21; ++j) a[j] = fmaf(h, wrow[j], a[j]);
}

// --- degree+count via ONE packed 64-bit atomic per edge ---
__global__ void deg_count_kernel(const int* __restrict__ row, const float* __restrict__ val,
                                 unsigned long long* __restrict__ dcpack,
                                 int* __restrict__ slot, int* __restrict__ invidx) {
    int e = blockIdx.x * 256 + threadIdx.x;
    if (e < NN) invidx[e] = -1;
    if (e < EE) {
        int r = row[e];
        unsigned long long add = (1ULL << 44) | (unsigned long long)(val[e] * 4294967296.0f);
        unsigned long long old = atomicAdd(&dcpack[r], add);
        slot[e] = (int)(old >> 44);
    }
}

// --- fused: unpack deg/cnt; dis; invidx; per-block degree histogram ---
__global__ void fused_setup_kernel(const unsigned long long* __restrict__ dcpack,
                                   float* __restrict__ dis,
                                   const int* __restrict__ index, int* __restrict__ invidx,
                                   int* __restrict__ cnt, int* __restrict__ blockhist) {
    __shared__ int lh[256];
    int tid = threadIdx.x;
    int i = blockIdx.x * 256 + tid;
    lh[tid] = 0;
    __syncthreads();
    if (i < MM) {
        unsigned long long pkv = dcpack[i];
        int v = (int)(pkv >> 44);
        float dsum = (float)(pkv & ((1ULL << 44) - 1)) * (1.0f / 4294967296.0f);
        dis[i] = rsqrtf(dsum + 1e-8f);
        invidx[index[i]] = i;
        cnt[i] = v;
        atomicAdd(&lh[min(v, 255)], 1);
    }
    __syncthreads();
    blockhist[tid * NB + blockIdx.x] = lh[tid];   // [deg][block]
}

// --- per-degree exclusive scan across blocks; one block per degree bin ---
__global__ void scan_bins_kernel(const int* __restrict__ blockhist,
                                 int* __restrict__ blockoff, int* __restrict__ total) {
    int d = blockIdx.x;       // 256 bins
    int lane = threadIdx.x;   // 64 threads
    int carry = 0;
    for (int base = 0; base < NB; base += 64) {
        int b = base + lane;
        int v = (b < NB) ? blockhist[d * NB + b] : 0;
        int x = v;
        #pragma unroll
        for (int off = 1; off < 64; off <<= 1) {
            int t = __shfl_up(x, off, 64);
            if (lane >= off) x += t;
        }
        if (b < NB) blockoff[d * NB + b] = carry + x - v;
        carry += __shfl(x, 63);
    }
    if (lane == 0) total[d] = carry;
}

// --- counting-sort finalize: per-row sorted position + padded CSR offset.
//     bin scans (row-count and pad4-size) recomputed per block from total[]. ---
__global__ void sort_rows_kernel(const int* __restrict__ cnt, const int* __restrict__ blockoff,
                                 const int* __restrict__ total, const int* __restrict__ index,
                                 int4* __restrict__ meta, int* __restrict__ row_s4) {
    __shared__ int lh[256], sbin[256], spad[256], ws[8];
    int tid = threadIdx.x, lane = tid & 63, w = tid >> 6;
    lh[tid] = 0;
    int t = total[tid];
    int v1 = t, v2 = t * ((tid + 3) & ~3);   // rows in bin; padded edges in bin
    int x1 = v1, x2 = v2;
    #pragma unroll
    for (int off = 1; off < 64; off <<= 1) {
        int t1 = __shfl_up(x1, off, 64);
        int t2 = __shfl_up(x2, off, 64);
        if (lane >= off) { x1 += t1; x2 += t2; }
    }
    if (lane == 63) { ws[w] = x1; ws[4 + w] = x2; }
    __syncthreads();
    int a1 = 0, a2 = 0;
    for (int q = 0; q < w; ++q) { a1 += ws[q]; a2 += ws[4 + q]; }
    sbin[tid] = a1 + x1 - v1;   // exclusive: first sorted pos of bin
    spad[tid] = a2 + x2 - v2;   // exclusive: first padded edge slot of bin
    __syncthreads();
    int i = blockIdx.x * 256 + tid;
    if (i < MM) {
        int d = cnt[i], c = min(d, 255);
        int lrank = atomicAdd(&lh[c], 1);
        int k = blockoff[c * NB + blockIdx.x] + lrank;  // global rank within bin
        int spos = sbin[c] + k;
        int s4 = spad[c] + k * ((d + 3) & ~3);
        // store descending by degree so heavy rows are scheduled first
        meta[MM - 1 - spos] = make_int4(s4, d, i, index[i]);
        row_s4[i] = s4;
    }
}

// --- bucket edges into padded sorted CSR (pads stay zero from memset) ---
__global__ void scatter_kernel(const int* __restrict__ row, const int* __restrict__ col,
                               const float* __restrict__ val, const float* __restrict__ dis,
                               const int* __restrict__ row_s4, const int* __restrict__ slot,
                               int* __restrict__ col_s, float* __restrict__ val_s) {
    int e = blockIdx.x * 256 + threadIdx.x;
    if (e < EE) {
        int r = row[e], c = col[e];
        int pos = row_s4[r] + slot[e];
        col_s[pos] = c;
        val_s[pos] = val[e] * dis[r] * dis[c];
    }
}

// --- X0b = bf16(features[index]); Xfull backfill for non-propagated nodes;
//     W1b/W2b = transposed packed bf16 weights ---
__global__ void cvt_kernel(const float* __restrict__ feat, const int* __restrict__ index,
                           const int* __restrict__ invidx,
                           unsigned* __restrict__ X0b, unsigned* __restrict__ Xfull,
                           const float* __restrict__ W1, const float* __restrict__ W2,
                           unsigned* __restrict__ W1b, unsigned* __restrict__ W2b) {
    int i = blockIdx.x * 256 + threadIdx.x;   // grid covers NN*64
    int n = i >> 6, u = i & 63;
    if (n < NN && invidx[n] < 0) {            // backfill: bf16(feat) row
        float2 f = ((const float2*)feat)[(size_t)n * 64 + u];
        Xfull[(size_t)n * 64 + u] = pk2(f.x, f.y);
    }
    if (i < MM * 64) {                        // X0b = bf16(feat[index])
        int idx = index[n];
        float2 f = ((const float2*)feat)[(size_t)idx * 64 + u];
        X0b[i] = pk2(f.x, f.y);
    }
    if (i < 4096) {          // W1^T: [j=0..63][kp=0..63]  (K=128)
        int j = i >> 6, kp = i & 63;
        W1b[i] = pk2(W1[(2 * kp) * 64 + j], W1[(2 * kp + 1) * 64 + j]);
    } else if (i < 5120) {   // W2^T: [j=0..31][kp=0..31]
        int t = i - 4096;
        int j = t >> 5, kp = t & 31;
        W2b[t] = pk2(W2[(2 * kp) * 32 + j], W2[(2 * kp + 1) * 32 + j]);
    }
}

// --- SpMM on bf16 tables: 16-lane group per sorted row, 4 groups/wave.
//     Branchless pad4 inner loop; (c,v) via L1-broadcast vector loads (no shuffles).
//     Degree-sorted rows => near-zero divergence within a wave. ---
__global__ __launch_bounds__(256) void spmm_kernel(
    const int4* __restrict__ meta, const int* __restrict__ cols,
    const float* __restrict__ vals, const unsigned short* __restrict__ X,
    unsigned short* __restrict__ Y, int use_remap) {
    int lane = threadIdx.x & 63;
    int wid = threadIdx.x >> 6;
    int g = lane >> 4, sub = lane & 15;
    int ri = blockIdx.x * 16 + wid * 4 + g;
    bool valid = (ri < MM);
    int rc = valid ? ri : (MM - 1);
    int4 mt = meta[rc];                  // {s4, deg, row, index[row]}
    int s = mt.x, d = mt.y;
    const uint4* __restrict__ X4 = (const uint4*)X;
    float a[8] = {0.f, 0.f, 0.f, 0.f, 0.f, 0.f, 0.f, 0.f};
    int e4 = s + d;
    for (int base = s; base < e4; base += 4) {
        int4 c4 = *(const int4*)(cols + base);     // same addr across 16 lanes -> L1 broadcast
        float4 v4 = *(const float4*)(vals + base); // pads: c=0, v=0 -> exact no-op fma
        uint4 u0 = X4[c4.x * 16 + sub];
        uint4 u1 = X4[c4.y * 16 + sub];
        uint4 u2 = X4[c4.z * 16 + sub];
        uint4 u3 = X4[c4.w * 16 + sub];
        fmab8(v4.x, u0, a);
        fmab8(v4.y, u1, a);
        fmab8(v4.z, u2, a);
        fmab8(v4.w, u3, a);
    }
    if (valid) {
        int dst = use_remap ? mt.w : mt.z;
        uint4 o;
        o.x = pk2(a[0], a[1]); o.y = pk2(a[2], a[3]);
        o.z = pk2(a[4], a[5]); o.w = pk2(a[6], a[7]);
        ((uint4*)Y)[dst * 16 + sub] = o;
    }
}

// --- MFMA MLP v3: 64 nodes/block (4 waves x 16 nodes), BARRIER-FREE.
//     A-frags: direct global loads from Xfull (consecutive 256B rows).
//     B-frags: direct global loads from pre-packed W1b/W2b (L2-hot).
//     LDS: per-wave private h1/h2 transpose buffer only (17408 B). ---
__global__ __launch_bounds__(256) void mlp_kernel(
    const unsigned* __restrict__ Xfull,
    const unsigned* __restrict__ W1b, const float* __restrict__ b1,
    const unsigned* __restrict__ W2b, const float* __restrict__ b2,
    const float* __restrict__ W3, const float* __restrict__ b3,
    const float* __restrict__ W4, float* __restrict__ out) {
    __shared__ float hls[4 * 1088];   // per-wave 16x68-f32 region
    int tid = threadIdx.x;
    int lane = tid & 63, w = tid >> 6;
    int p = lane & 15, q = lane >> 4;
    float* hw = hls + w * 1088;
    int nb = blockIdx.x * 64;
    int node = nb + w * 16 + p;       // guaranteed < NNP (padded table)

    // ---- L1: A direct from Xfull, B direct from W1b ----
    bf16x8 af[4];
    #pragma unroll
    for (int kc = 0; kc < 4; ++kc) {
        uint4 u = *(const uint4*)(Xfull + (size_t)node * 64 + kc * 16 + q * 4);
        af[kc] = *(const bf16x8*)&u;
    }
    f32x4 acc[4];
    #pragma unroll
    for (int jt = 0; jt < 4; ++jt) {
        float bv = b1[jt * 16 + p];
        acc[jt][0] = bv; acc[jt][1] = bv; acc[jt][2] = bv; acc[jt][3] = bv;
    }
    #pragma unroll
    for (int jt = 0; jt < 4; ++jt) {
        #pragma unroll
        for (int kc = 0; kc < 4; ++kc) {
            uint4 u = *(const uint4*)(W1b + (jt * 16 + p) * 64 + kc * 16 + q * 4);
            bf16x8 bf = *(const bf16x8*)&u;
            acc[jt] = __builtin_amdgcn_mfma_f32_16x16x32_bf16(af[kc], bf, acc[jt], 0, 0, 0);
        }
    }
    // h1 -> wave-private LDS (C layout: node=q*4+r, col=jt*16+p); leaky ReLU
    #pragma unroll
    for (int jt = 0; jt < 4; ++jt) {
        #pragma unroll
        for (int r = 0; r < 4; ++r) {
            float v = acc[jt][r];
            v = v > 0.f ? v : 0.01f * v;
            hw[(q * 4 + r) * 68 + jt * 16 + p] = v;
        }
    }
    // ---- L2: A from hw (pack f32->bf16), B direct from W2b ----
    bf16x8 a2f[2];
    #pragma unroll
    for (int kc = 0; kc < 2; ++kc) {
        const float* hp = hw + p * 68 + kc * 32 + q * 8;
        f32x4 v0 = *(const f32x4*)hp;
        f32x4 v1 = *(const f32x4*)(hp + 4);
        uint4 uu = make_uint4(pk2(v0[0], v0[1]), pk2(v0[2], v0[3]),
                              pk2(v1[0], v1[1]), pk2(v1[2], v1[3]));
        a2f[kc] = *(const bf16x8*)&uu;
    }
    f32x4 acc2[2];
    #pragma unroll
    for (int jt = 0; jt < 2; ++jt) {
        float bv = b2[jt * 16 + p];
        acc2[jt][0] = bv; acc2[jt][1] = bv; acc2[jt][2] = bv; acc2[jt][3] = bv;
        #pragma unroll
        for (int kc = 0; kc < 2; ++kc) {
            uint4 u = *(const uint4*)(W2b + (jt * 16 + p) * 32 + kc * 16 + q * 4);
            bf16x8 bf = *(const bf16x8*)&u;
            acc2[jt] = __builtin_amdgcn_mfma_f32_16x16x32_bf16(a2f[kc], bf, acc2[jt], 0, 0, 0);
        }
    }
    // h2 -> same wave-private LDS (all h1 reads by this wave precede, in-order LDS)
    #pragma unroll
    for (int jt = 0; jt < 2; ++jt) {
        #pragma unroll
        for (int r = 0; r < 4; ++r) {
            float v = acc2[jt][r];
            v = v > 0.f ? v : 0.01f * v;
            hw[(q * 4 + r) * 36 + jt * 16 + p] = v;
        }
    }
    // ---- L3+L4 scalar tail (q-groups redundant; W3/W4 via s_load) ----
    float a3[21];
    #pragma unroll
    for (int j = 0; j < 21; ++j) a3[j] = b3[j];
    #pragma unroll 4
    for (int k = 0; k < 32; ++k) {
        float hk = hw[p * 36 + k];
        fma21(hk, W3 + k * 21, a3);
    }
    float s = 0.f;
    #pragma unroll
    for (int j = 0; j < 21; ++j) {
        float vj = a3[j] > 0.f ? a3[j] : 0.01f * a3[j];
        s = fmaf(vj, W4[j], s);
    }
    if (q == 0) {
        int n = nb + w * 16 + p;
        if (n < NN) out[n] = 1.f / (1.f + expf(-s));
    }
}

extern "C" void kernel_launch(void* const* d_in, const int* in_sizes, int n_in,
                              void* d_out, int out_size, void* d_ws, size_t ws_size,
                              hipStream_t stream) {
    const float* feat = (const float*)d_in[0];
    const int*   index = (const int*)d_in[1];
    const int*   erow = (const int*)d_in[2];
    const int*   ecol = (const int*)d_in[3];
    const float* evalp = (const float*)d_in[4];
    const float* W1 = (const float*)d_in[5];
    const float* b1 = (const float*)d_in[6];
    const float* W2 = (const float*)d_in[7];
    const float* b2 = (const float*)d_in[8];
    const float* W3 = (const float*)d_in[9];
    const float* b3 = (const float*)d_in[10];
    const float* W4 = (const float*)d_in[11];
    float* out = (float*)d_out;

    char* ws = (char*)d_ws;
    size_t off = 0;
    auto alloc = [&](size_t bytes) -> void* {
        void* p = ws + off;
        off += (bytes + 255) & ~(size_t)255;
        return p;
    };
    // first three contiguous: single zeroing memset covers them
    unsigned long long* dcpack = (unsigned long long*)alloc((size_t)MM * 8);
    int*   col_s   = (int*)  alloc((size_t)EE4 * 4);
    float* val_s   = (float*)alloc((size_t)EE4 * 4);
    size_t zero_span = (size_t)((char*)val_s - (char*)dcpack) + (size_t)EE4 * 4;

    float* dis     = (float*)alloc((size_t)MM * 4);
    int*   cnt     = (int*)  alloc((size_t)MM * 4);
    int*   slot    = (int*)  alloc((size_t)EE * 4);
    int*   invidx  = (int*)  alloc((size_t)NN * 4);
    int*   row_s4  = (int*)  alloc((size_t)MM * 4);
    int*   blockhist = (int*)alloc((size_t)256 * NB * 4);
    int*   blockoff  = (int*)alloc((size_t)256 * NB * 4);
    int*   total     = (int*)alloc((size_t)256 * 4);
    int4*  meta      = (int4*)alloc((size_t)MM * 16);
    unsigned* W1b  = (unsigned*)alloc(4096 * 4);
    unsigned* W2b  = (unsigned*)alloc(1024 * 4);
    unsigned*       X0b   = (unsigned*)      alloc((size_t)MM * DD * 2);
    unsigned short* Xa    = (unsigned short*)alloc((size_t)MM * DD * 2);
    unsigned short* Xb    = (unsigned short*)alloc((size_t)MM * DD * 2);
    unsigned*       Xfull = (unsigned*)      alloc((size_t)NNP * DD * 2);

    hipMemsetAsync(dcpack, 0, zero_span, stream);

    deg_count_kernel<<<(EE + 255) / 256, 256, 0, stream>>>(erow, evalp, dcpack, slot, invidx);
    fused_setup_kernel<<<NB, 256, 0, stream>>>(dcpack, dis, index, invidx, cnt, blockhist);
    scan_bins_kernel<<<256, 64, 0, stream>>>(blockhist, blockoff, total);
    sort_rows_kernel<<<NB, 256, 0, stream>>>(cnt, blockoff, total, index, meta, row_s4);
    scatter_kernel<<<(EE + 255) / 256, 256, 0, stream>>>(erow, ecol, evalp, dis,
                                                         row_s4, slot, col_s, val_s);
    cvt_kernel<<<(NN * 64 + 255) / 256, 256, 0, stream>>>(feat, index, invidx, X0b, Xfull,
                                                          W1, W2, W1b, W2b);

    spmm_kernel<<<(MM + 15) / 16, 256, 0, stream>>>(meta, col_s, val_s,
                                                    (const unsigned short*)X0b, Xa, 0);
    spmm_kernel<<<(MM + 15) / 16, 256, 0, stream>>>(meta, col_s, val_s, Xa, Xb, 0);
    spmm_kernel<<<(MM + 15) / 16, 256, 0, stream>>>(meta, col_s, val_s, Xb,
                                                    (unsigned short*)Xfull, 1);

    mlp_kernel<<<(NNP + 63) / 64, 256, 0, stream>>>(Xfull, W1b, b1, W2b, b2,
                                                    W3, b3, W4, out);
}